// Round 5
// baseline (204.838 us; speedup 1.0000x reference)
//
#include <hip/hip_runtime.h>

// BConv2d: x (32,32,256,256) f32 NCHW, W (32,32,3,3) binarized to +-1,
// 3x3 'same' conv, out / sqrt(288).
//
// R4 base (clean traffic: 512 blocks, 64x64 tiles, XOR-swizzled
// [slot][px][ci-octet] LDS, reg-pipelined staging, 1 barrier/iter) +
// VMEM smoothing: tp-outer compute so each px-tile's stores issue right
// after its 9 MFMAs, staging loads split into 3 chunks interleaved between
// tile groups (sched_barrier-pinned), last iteration peeled so the loop
// body has unconditional loads (precise waitcnts).

typedef __attribute__((ext_vector_type(8))) short short8;
typedef __attribute__((ext_vector_type(4))) float f32x4;

__device__ __forceinline__ short bf16s(float f) {
    unsigned int u = __builtin_bit_cast(unsigned int, f);
    u += 0x7FFFu + ((u >> 16) & 1u);   // RNE
    return (short)(u >> 16);
}

__global__ __launch_bounds__(512, 4)
void bconv2d_kernel(const float* __restrict__ x, const float* __restrict__ wgt,
                    float* __restrict__ out) {
    // unit = slot*264 + pl*4 + (u ^ ((pl>>1)&3)); slot = row_local % 12,
    // row_local = gy - Y0 + 1; pl = 0..65. Bank-clean for px-consecutive b128
    // writes and fragment b128 reads (verified: 0 conflicts in R4).
    __shared__ short8 lds[12 * 264];   // 50688 B

    const int tid = threadIdx.x;
    const int gx0 = blockIdx.x * 64;
    const int Y0  = blockIdx.y * 64;
    const int n   = blockIdx.z;

    const int l      = tid & 63;
    const int wv     = tid >> 6;
    const int r      = wv & 3;         // row within 4-row step
    const int ch     = wv >> 2;        // co half
    const int lane15 = l & 15;
    const int lhi    = l >> 4;

    // ---- A fragments: sign(W), this wave's co-half, all 9 taps ----
    short8 afrag[3][3];
    {
        const int co  = ch * 16 + lane15;
        const int ci0 = lhi * 8;
        #pragma unroll
        for (int dy = 0; dy < 3; ++dy)
            #pragma unroll
            for (int dx = 0; dx < 3; ++dx) {
                short8 a;
                #pragma unroll
                for (int j = 0; j < 8; ++j) {
                    float wval = wgt[((co * 32 + ci0 + j) * 3 + dy) * 3 + dx];
                    a[j] = (short)((wval > 0.0f) ? 0x3F80 : 0xBF80);
                }
                afrag[dy][dx] = a;
            }
    }

    const float* xn = x + (size_t)n * 32 * 65536;

    // staging ownership: interior task t = tid + k*512 (k=0,1):
    //   rr=t>>8, u=(t>>6)&3, pl=1+(t&63); edge (tid>=480): e=tid-480:
    //   rr=e>>3, u=(e>>1)&3, side=e&1 -> pl 0 or 65
    float rg[2][8];     // pending interior loads
    float re[8];        // pending edge loads (upper half of wave 7)

    auto load_int = [&](int s, int k) {     // interior chunk k of stage s
        const int bg = Y0 + 4 * s - 1;
        const int t  = tid + k * 512;
        const int rr = t >> 8;
        const int u  = (t >> 6) & 3;
        const int pl = 1 + (t & 63);
        const int gy = bg + rr;
        if ((unsigned)gy < 256u) {
            const float* src = xn + ((size_t)(u * 8) * 256 + gy) * 256 + gx0 + (pl - 1);
            #pragma unroll
            for (int j = 0; j < 8; ++j) rg[k][j] = src[(size_t)j * 65536];
        } else {
            #pragma unroll
            for (int j = 0; j < 8; ++j) rg[k][j] = 0.0f;
        }
    };
    auto load_edge = [&](int s) {
        if (tid >= 480) {
            const int bg   = Y0 + 4 * s - 1;
            const int e    = tid - 480;
            const int rr   = e >> 3;
            const int u    = (e >> 1) & 3;
            const int side = e & 1;
            const int gy   = bg + rr;
            const int gx   = side ? gx0 + 64 : gx0 - 1;
            if ((unsigned)gy < 256u && (unsigned)gx < 256u) {
                const float* src = xn + ((size_t)(u * 8) * 256 + gy) * 256 + gx;
                #pragma unroll
                for (int j = 0; j < 8; ++j) re[j] = src[(size_t)j * 65536];
            } else {
                #pragma unroll
                for (int j = 0; j < 8; ++j) re[j] = 0.0f;
            }
        }
    };

    auto stage_write = [&](int s) {
        const int slot0 = 4 * (s % 3);
        #pragma unroll
        for (int k = 0; k < 2; ++k) {
            const int t  = tid + k * 512;
            const int rr = t >> 8;
            const int u  = (t >> 6) & 3;
            const int pl = 1 + (t & 63);
            short8 v;
            #pragma unroll
            for (int j = 0; j < 8; ++j) v[j] = bf16s(rg[k][j]);
            lds[(slot0 + rr) * 264 + pl * 4 + (u ^ ((pl >> 1) & 3))] = v;
        }
        if (tid >= 480) {
            const int e    = tid - 480;
            const int rr   = e >> 3;
            const int u    = (e >> 1) & 3;
            const int side = e & 1;
            const int pl   = side ? 65 : 0;
            short8 v;
            #pragma unroll
            for (int j = 0; j < 8; ++j) v[j] = bf16s(re[j]);
            lds[(slot0 + rr) * 264 + pl * 4 + (u ^ ((pl >> 1) & 3))] = v;
        }
    };

    const float invdiv = 0.05892556509887896f;   // 1/sqrt(288)

    // one px-tile: 9 MFMAs then 4 stores
    auto tile = [&](int i, int i3, int tp) {
        f32x4 acc = (f32x4)0.0f;
        #pragma unroll
        for (int ss = 0; ss < 3; ++ss) {
            int m = 4 * i3 + r + ss;              // row_local % 12
            if (m >= 12) m -= 12;
            const int sbase = m * 264;
            #pragma unroll
            for (int dx = 0; dx < 3; ++dx) {
                const int pl = tp * 16 + lane15 + dx;
                short8 b = lds[sbase + pl * 4 + (lhi ^ ((pl >> 1) & 3))];
                acc = __builtin_amdgcn_mfma_f32_16x16x32_bf16(
                    afrag[ss][dx], b, acc, 0, 0, 0);
            }
        }
        const int y = Y0 + 4 * i + r;
        #pragma unroll
        for (int q = 0; q < 4; ++q) {
            const int co = ch * 16 + lhi * 4 + q;
            out[(((size_t)n * 32 + co) * 256 + y) * 256 + gx0 + tp * 16 + lane15]
                = acc[q] * invdiv;
        }
    };

    // ---- prologue: R(0) loaded+written; R(1) loaded (pending) ----
    load_int(0, 0); load_int(0, 1); load_edge(0);
    stage_write(0);
    load_int(1, 0); load_int(1, 1); load_edge(1);

    int i3 = 0;
    for (int i = 0; i < 15; ++i) {
        stage_write(i + 1);                       // drains loads from iter i-1
        __syncthreads();

        tile(i, i3, 0);
        load_int(i + 2, 0);
        __builtin_amdgcn_sched_barrier(0);
        tile(i, i3, 1);
        load_int(i + 2, 1);
        __builtin_amdgcn_sched_barrier(0);
        tile(i, i3, 2);
        load_edge(i + 2);
        __builtin_amdgcn_sched_barrier(0);
        tile(i, i3, 3);

        i3 = (i3 == 2) ? 0 : i3 + 1;
    }

    // ---- peeled last iteration (no loads) ----
    stage_write(16);
    __syncthreads();
    tile(15, i3, 0);
    tile(15, i3, 1);
    tile(15, i3, 2);
    tile(15, i3, 3);
}

extern "C" void kernel_launch(void* const* d_in, const int* in_sizes, int n_in,
                              void* d_out, int out_size, void* d_ws, size_t ws_size,
                              hipStream_t stream) {
    const float* x   = (const float*)d_in[0];
    const float* wgt = (const float*)d_in[1];
    float* out = (float*)d_out;
    (void)d_ws; (void)ws_size;
    dim3 grid(4, 4, 32);    // 64px x-strips, 64-row y-strips, images
    dim3 block(512);
    bconv2d_kernel<<<grid, block, 0, stream>>>(x, wgt, out);
}

// Round 6
// 140.006 us; speedup vs baseline: 1.4631x; 1.4631x over previous
//
#include <hip/hip_runtime.h>

// BConv2d: x (32,32,256,256) f32 NCHW, W (32,32,3,3) binarized to +-1,
// 3x3 'same' conv, out / sqrt(288).
//
// R6: full-width tiles for DRAM stream locality. Block = one image x 16 output
// rows x 256 px x all 32 co. Per staging step each channel plane is read as a
// 1KB contiguous run (vs 256B before); per store burst each co plane gets a
// 256B contiguous run per wave (full 128B lines, wave-local write-merge).
// 4-slot rolling row window in LDS (66KB), 1 barrier/iter, 512 blocks.

typedef __attribute__((ext_vector_type(8))) short short8;
typedef __attribute__((ext_vector_type(4))) float f32x4;

__device__ __forceinline__ short bf16s(float f) {
    unsigned int u = __builtin_bit_cast(unsigned int, f);
    u += 0x7FFFu + ((u >> 16) & 1u);   // RNE
    return (short)(u >> 16);
}

__global__ __launch_bounds__(512, 4)
void bconv2d_kernel(const float* __restrict__ x, const float* __restrict__ wgt,
                    float* __restrict__ out) {
    // unit = slot*1032 + pl*4 + (u ^ ((pl>>1)&3)); slot = gy & 3; pl = gx+1
    // (0..257); u = ci/8. Same swizzle family as R4 (verified 0 conflicts).
    __shared__ short8 lds[4 * 1032];   // 66048 B

    const int tid = threadIdx.x;
    const int y0  = blockIdx.x * 16;   // 16-row strip
    const int n   = blockIdx.y;        // image

    const int l      = tid & 63;
    const int wv     = tid >> 6;       // 0..7
    const int seg    = wv >> 1;        // px segment (64 px)
    const int ch     = wv & 1;         // co half
    const int px0    = seg * 64;
    const int lane15 = l & 15;
    const int lhi    = l >> 4;

    // ---- A fragments: sign(W), this wave's co-half, all 9 taps ----
    short8 afrag[3][3];
    {
        const int co  = ch * 16 + lane15;
        const int ci0 = lhi * 8;
        #pragma unroll
        for (int dy = 0; dy < 3; ++dy)
            #pragma unroll
            for (int dx = 0; dx < 3; ++dx) {
                short8 a;
                #pragma unroll
                for (int j = 0; j < 8; ++j) {
                    float wval = wgt[((co * 32 + ci0 + j) * 3 + dy) * 3 + dx];
                    a[j] = (short)((wval > 0.0f) ? 0x3F80 : 0xBF80);
                }
                afrag[dy][dx] = a;
            }
    }

    const float* xn = x + (size_t)n * 32 * 65536;

    // staging ownership (fixed): k=0,1: t = tid + k*512 (0..1023):
    //   u = t>>8 (ci octet), gx = t&255, pl = gx+1.
    // Whole block reads each plane-row as one contiguous 1KB run.
    float rg[2][8];

    auto load_row = [&](int gy) {
        if ((unsigned)gy < 256u) {
            #pragma unroll
            for (int k = 0; k < 2; ++k) {
                const int t  = tid + k * 512;
                const int u  = t >> 8;
                const int gx = t & 255;
                const float* src = xn + ((size_t)(u * 8) * 256 + gy) * 256 + gx;
                #pragma unroll
                for (int j = 0; j < 8; ++j) rg[k][j] = src[(size_t)j * 65536];
            }
        } else {
            #pragma unroll
            for (int k = 0; k < 2; ++k)
                #pragma unroll
                for (int j = 0; j < 8; ++j) rg[k][j] = 0.0f;
        }
    };

    auto write_row = [&](int slot) {
        #pragma unroll
        for (int k = 0; k < 2; ++k) {
            const int t  = tid + k * 512;
            const int u  = t >> 8;
            const int pl = 1 + (t & 255);
            short8 v;
            #pragma unroll
            for (int j = 0; j < 8; ++j) v[j] = bf16s(rg[k][j]);
            lds[slot * 1032 + pl * 4 + (u ^ ((pl >> 1) & 3))] = v;
        }
    };

    // ---- prologue: rows y0-1, y0, y0+1 -> slots (y&3); zero the px edges ----
    load_row(y0 - 1); write_row((y0 - 1) & 3);
    load_row(y0);     write_row(y0 & 3);
    load_row(y0 + 1); write_row((y0 + 1) & 3);
    if (tid < 32) {   // pl=0 (gx=-1) and pl=257 (gx=256) are always zero
        const int slot = tid & 3;
        const int u    = (tid >> 2) & 3;
        const int pl   = (tid >> 4) ? 257 : 0;
        lds[slot * 1032 + pl * 4 + u] = (short8)0;   // swizzle term = 0 for these pl
    }
    __syncthreads();

    const float invdiv = 0.05892556509887896f;   // 1/sqrt(288)

    #pragma unroll 4
    for (int yy = 0; yy < 16; ++yy) {
        const int y = y0 + yy;

        load_row(y + 2);                 // issue early; no dependency until write_row

        f32x4 acc[4];
        #pragma unroll
        for (int tp = 0; tp < 4; ++tp) acc[tp] = (f32x4)0.0f;

        #pragma unroll
        for (int ss = 0; ss < 3; ++ss) {            // input row y-1+ss
            const int m     = (yy + ss + 3) & 3;    // slot (y0%4==0)
            const int sbase = m * 1032;
            #pragma unroll
            for (int dx = 0; dx < 3; ++dx)
                #pragma unroll
                for (int tp = 0; tp < 4; ++tp) {
                    const int pl = px0 + tp * 16 + lane15 + dx;
                    short8 b = lds[sbase + pl * 4 + (lhi ^ ((pl >> 1) & 3))];
                    acc[tp] = __builtin_amdgcn_mfma_f32_16x16x32_bf16(
                        afrag[ss][dx], b, acc[tp], 0, 0, 0);
                }
        }

        write_row((yy + 2) & 3);         // vmcnt wait lands after compute

        // stores: per wave, each of its 4 co planes gets px0..px0+63 (256B run)
        #pragma unroll
        for (int tp = 0; tp < 4; ++tp)
            #pragma unroll
            for (int q = 0; q < 4; ++q) {
                const int co = ch * 16 + lhi * 4 + q;
                out[(((size_t)n * 32 + co) * 256 + y) * 256 + px0 + tp * 16 + lane15]
                    = acc[tp][q] * invdiv;
            }

        __syncthreads();   // row y+2 visible; slot (yy+2)&3 not read until next iter
    }
}

extern "C" void kernel_launch(void* const* d_in, const int* in_sizes, int n_in,
                              void* d_out, int out_size, void* d_ws, size_t ws_size,
                              hipStream_t stream) {
    const float* x   = (const float*)d_in[0];
    const float* wgt = (const float*)d_in[1];
    float* out = (float*)d_out;
    (void)d_ws; (void)ws_size;
    dim3 grid(16, 32);     // 16-row strips, images
    dim3 block(512);
    bconv2d_kernel<<<grid, block, 0, stream>>>(x, wgt, out);
}